// Round 6
// baseline (368.736 us; speedup 1.0000x reference)
//
#include <hip/hip_runtime.h>
#include <math.h>

typedef unsigned int uint_t;

#define BK_SHIFT 7
#define BK_NODES 128
#define MAXBK 512          // supports N <= 65536
#define PART_CHUNK 4096
#define SORT_CAP 4096

__device__ __forceinline__ float lrelu(float x){ return x > 0.f ? x : 0.2f*x; }
__device__ __forceinline__ float sel4(float a, float b, float c, float d, int h){
    return h==0 ? a : (h==1 ? b : (h==2 ? c : d));
}
__device__ __forceinline__ float wmax(float v){
    #pragma unroll
    for (int m = 1; m < 64; m <<= 1) v = fmaxf(v, __shfl_xor(v, m));
    return v;
}
__device__ __forceinline__ float wsum(float v){
    #pragma unroll
    for (int m = 1; m < 64; m <<= 1) v += __shfl_xor(v, m);
    return v;
}
__device__ __forceinline__ uint_t pack_bf2(float a, float b){
    uint_t ua = __float_as_uint(a); uint_t ub = __float_as_uint(b);
    ua += 0x7FFFu + ((ua >> 16) & 1u);
    ub += 0x7FFFu + ((ub >> 16) & 1u);
    return (ua >> 16) | (ub & 0xFFFF0000u);
}
__device__ __forceinline__ float bflo(uint_t u){ return __uint_as_float(u << 16); }
__device__ __forceinline__ float bfhi(uint_t u){ return __uint_as_float(u & 0xFFFF0000u); }

// ---------------- CSR build ----------------

__global__ void hist_kernel(const int* __restrict__ ei, int E, int N, int* __restrict__ deg){
    int idx = blockIdx.x * blockDim.x + threadIdx.x;
    if (idx >= E + N) return;
    int d = (idx < E) ? ei[E + idx] : (idx - E);
    atomicAdd(&deg[d], 1);
}

__global__ __launch_bounds__(256) void scan_blocksum(const int* __restrict__ deg,
                                                     int* __restrict__ bsum, int N){
    int b = blockIdx.x, t = threadIdx.x;
    int base = b * 1024 + t * 4;
    int s = 0;
    #pragma unroll
    for (int i = 0; i < 4; ++i){ int idx = base + i; if (idx < N) s += deg[idx]; }
    __shared__ int sm[256];
    sm[t] = s; __syncthreads();
    for (int off = 128; off > 0; off >>= 1){
        if (t < off) sm[t] += sm[t + off];
        __syncthreads();
    }
    if (t == 0) bsum[b] = sm[0];
}

__global__ __launch_bounds__(1024) void scan_partials(int* __restrict__ bsum, int NB,
                                                      int* __restrict__ indptr, int N){
    int t = threadIdx.x;
    int v = (t < NB) ? bsum[t] : 0;
    __shared__ int sm[1024];
    sm[t] = v; __syncthreads();
    for (int off = 1; off < 1024; off <<= 1){
        int u = (t >= off) ? sm[t - off] : 0;
        __syncthreads();
        sm[t] += u;
        __syncthreads();
    }
    if (t < NB) bsum[t] = (t == 0) ? 0 : sm[t - 1];
    if (t == NB - 1) indptr[N] = sm[t];
}

// also seeds gcursor[b] = indptr[b*128]
__global__ __launch_bounds__(256) void scan_final(const int* __restrict__ deg,
                                                  const int* __restrict__ bsum,
                                                  int* __restrict__ indptr,
                                                  int* __restrict__ gcursor, int N){
    int b = blockIdx.x, t = threadIdx.x;
    int base = b * 1024 + t * 4;
    int v0 = 0, v1 = 0, v2 = 0, v3 = 0;
    if (base + 0 < N) v0 = deg[base + 0];
    if (base + 1 < N) v1 = deg[base + 1];
    if (base + 2 < N) v2 = deg[base + 2];
    if (base + 3 < N) v3 = deg[base + 3];
    int s = v0 + v1 + v2 + v3;
    __shared__ int sm[256];
    sm[t] = s; __syncthreads();
    for (int off = 1; off < 256; off <<= 1){
        int u = (t >= off) ? sm[t - off] : 0;
        __syncthreads();
        sm[t] += u;
        __syncthreads();
    }
    int run = bsum[b] + ((t == 0) ? 0 : sm[t - 1]);
    #pragma unroll
    for (int i = 0; i < 4; ++i){
        int idx = base + i;
        int v = (i == 0) ? v0 : (i == 1) ? v1 : (i == 2) ? v2 : v3;
        if (idx < N){
            indptr[idx] = run;
            if ((idx & (BK_NODES - 1)) == 0) gcursor[idx >> BK_SHIFT] = run;
            run += v;
        }
    }
}

// phase A: partition packed (src | dlow<<25) into bucket-contiguous pairbuf
__global__ __launch_bounds__(256) void partition_kernel(
        const int* __restrict__ ei, int E, int N,
        int* __restrict__ gcursor, uint_t* __restrict__ pairbuf, int NBK){
    __shared__ int hist[MAXBK];
    __shared__ int sA[MAXBK];
    __shared__ int sB[MAXBK];
    __shared__ int destadj[MAXBK];
    __shared__ int cnt2[MAXBK];
    __shared__ uint_t staged[PART_CHUNK];
    int t = threadIdx.x;
    int base = blockIdx.x * PART_CHUNK;
    int total = E + N;
    int cnt = total - base; if (cnt > PART_CHUNK) cnt = PART_CHUNK; if (cnt < 0) cnt = 0;

    for (int i = t; i < MAXBK; i += 256){ hist[i] = 0; cnt2[i] = 0; }
    __syncthreads();
    for (int i = t; i < cnt; i += 256){
        int idx = base + i;
        int d = (idx < E) ? ei[E + idx] : (idx - E);
        atomicAdd(&hist[d >> BK_SHIFT], 1);
    }
    __syncthreads();
    sA[t] = hist[t]; sA[t + 256] = hist[t + 256];
    __syncthreads();
    int* psrc = sA; int* pdst = sB;
    for (int off = 1; off < MAXBK; off <<= 1){
        int i0 = t, i1 = t + 256;
        pdst[i0] = psrc[i0] + ((i0 >= off) ? psrc[i0 - off] : 0);
        pdst[i1] = psrc[i1] + ((i1 >= off) ? psrc[i1 - off] : 0);
        __syncthreads();
        int* tmp = psrc; psrc = pdst; pdst = tmp;
    }
    for (int b = t; b < NBK; b += 256){
        int c = hist[b];
        int gstart = (b == 0) ? 0 : psrc[b - 1];
        int rbase = c > 0 ? atomicAdd(&gcursor[b], c) : 0;
        destadj[b] = rbase - gstart;
        cnt2[b] = gstart;
    }
    __syncthreads();
    for (int i = t; i < cnt; i += 256){
        int idx = base + i;
        int d, s;
        if (idx < E){ s = ei[idx]; d = ei[E + idx]; }
        else        { s = d = idx - E; }
        int b = d >> BK_SHIFT;
        int pos = atomicAdd(&cnt2[b], 1);
        staged[pos] = (uint_t)s | ((uint_t)(d & (BK_NODES - 1)) << 25);
    }
    __syncthreads();
    for (int p = t; p < cnt; p += 256){
        uint_t pr = staged[p];
        // recompute bucket: need d's bucket; stage high bits carry only dlow, so
        // find bucket by position: bucket b covers staged range [startb, startb+hist[b]).
        // Instead: binary search is overkill — store bucket via psrc ranges.
        // Simpler: recover via search over destadj? Use the scan array psrc:
        // p < psrc[b] for the first b with psrc[b] > p.
        int lo = 0, hi = NBK - 1;
        while (lo < hi){
            int mid = (lo + hi) >> 1;
            if (p < psrc[mid]) hi = mid; else lo = mid + 1;
        }
        pairbuf[destadj[lo] + p] = pr;
    }
}

// phase B: per-bucket counting sort into final CSR srcs
__global__ __launch_bounds__(256) void bucket_sort_kernel(
        const uint_t* __restrict__ pairbuf, const int* __restrict__ indptr,
        int* __restrict__ srcs, int N, int NBK){
    int b = blockIdx.x;
    int nb = b << BK_SHIFT;
    int nend = nb + BK_NODES; if (nend > N) nend = N;
    int beg = indptr[nb], end = indptr[nend];
    int cnt = end - beg;
    __shared__ int lptr[BK_NODES];
    __shared__ int outb[SORT_CAP];
    int t = threadIdx.x;
    if (t < BK_NODES){
        int node = nb + t;
        lptr[t] = (node < N) ? (indptr[node] - beg) : 0;
    }
    __syncthreads();
    if (cnt <= SORT_CAP){
        for (int i = t; i < cnt; i += 256){
            uint_t pr = pairbuf[beg + i];
            int pos = atomicAdd(&lptr[(int)(pr >> 25)], 1);
            outb[pos] = (int)(pr & 0x1FFFFFFu);
        }
        __syncthreads();
        for (int i = t; i < cnt; i += 256) srcs[beg + i] = outb[i];
    } else {
        for (int i = t; i < cnt; i += 256){
            uint_t pr = pairbuf[beg + i];
            int pos = atomicAdd(&lptr[(int)(pr >> 25)], 1);
            srcs[beg + pos] = (int)(pr & 0x1FFFFFFu);
        }
    }
}

// ---------------- layer-1 linear (K=3): xp packed bf16x2 ----------------
__global__ __launch_bounds__(128) void linear_al(
        const float* __restrict__ in, const float* __restrict__ W,
        const float* __restrict__ as_, const float* __restrict__ ad_,
        uint_t* __restrict__ xp16, float* __restrict__ als, float* __restrict__ ald,
        int N, int K){
    __shared__ float hs[8 * 3];
    int t = threadIdx.x;
    int base = blockIdx.x * 8;
    int rows = N - base; if (rows > 8) rows = 8;
    for (int idx = t; idx < rows * K; idx += 128){
        int r = idx / K, k = idx - r * K;
        hs[r * K + k] = in[(size_t)(base + r) * K + k];
    }
    __syncthreads();
    float acc[8] = {0.f,0.f,0.f,0.f,0.f,0.f,0.f,0.f};
    for (int k = 0; k < K; ++k){
        float w = W[k * 128 + t];
        #pragma unroll
        for (int r = 0; r < 8; ++r) acc[r] += hs[r * K + k] * w;
    }
    float asv = as_[t], adv = ad_[t];
    for (int r = 0; r < rows; ++r){
        int row = base + r;
        float v = acc[r];
        float vo = __shfl_xor(v, 1);
        if (!(t & 1)) xp16[(size_t)row * 64 + (t >> 1)] = pack_bf2(v, vo);
        float vs = v * asv, vd = v * adv;
        #pragma unroll
        for (int m = 16; m >= 1; m >>= 1){
            vs += __shfl_xor(vs, m);
            vd += __shfl_xor(vd, m);
        }
        if ((t & 31) == 0){
            int h = t >> 5;
            als[row * 4 + h] = vs;
            ald[row * 4 + h] = vd;
        }
    }
}

// ---------------- K=128 linear: register-tiled fp32 GEMM + fused als/ald ----------------
__global__ __launch_bounds__(256) void gemm128_al(
        const float* __restrict__ in, const float* __restrict__ W,
        const float* __restrict__ as_, const float* __restrict__ ad_,
        uint_t* __restrict__ xp16, float* __restrict__ als, float* __restrict__ ald,
        int N){
    __shared__ float Xs[32][128];
    int t = threadIdx.x;
    int base = blockIdx.x * 32;
    int rows = N - base; if (rows > 32) rows = 32;
    for (int f = t; f < 1024; f += 256){
        int r = f >> 5, q = f & 31;
        float4 v = (r < rows) ? ((const float4*)(in + (size_t)(base + r) * 128))[q]
                              : make_float4(0.f,0.f,0.f,0.f);
        ((float4*)Xs)[f] = v;
    }
    __syncthreads();
    int cg = t & 31;
    int rg = t >> 5;
    float acc[4][4];
    #pragma unroll
    for (int i = 0; i < 4; ++i)
        #pragma unroll
        for (int j = 0; j < 4; ++j) acc[i][j] = 0.f;

    const float4* W4 = (const float4*)W;
    for (int k4 = 0; k4 < 32; ++k4){
        float4 w0 = W4[(4*k4+0)*32 + cg];
        float4 w1 = W4[(4*k4+1)*32 + cg];
        float4 w2 = W4[(4*k4+2)*32 + cg];
        float4 w3 = W4[(4*k4+3)*32 + cg];
        #pragma unroll
        for (int i = 0; i < 4; ++i){
            float4 xv = ((const float4*)(&Xs[4*rg + i][0]))[k4];
            acc[i][0] = fmaf(xv.x, w0.x, acc[i][0]);
            acc[i][0] = fmaf(xv.y, w1.x, acc[i][0]);
            acc[i][0] = fmaf(xv.z, w2.x, acc[i][0]);
            acc[i][0] = fmaf(xv.w, w3.x, acc[i][0]);
            acc[i][1] = fmaf(xv.x, w0.y, acc[i][1]);
            acc[i][1] = fmaf(xv.y, w1.y, acc[i][1]);
            acc[i][1] = fmaf(xv.z, w2.y, acc[i][1]);
            acc[i][1] = fmaf(xv.w, w3.y, acc[i][1]);
            acc[i][2] = fmaf(xv.x, w0.z, acc[i][2]);
            acc[i][2] = fmaf(xv.y, w1.z, acc[i][2]);
            acc[i][2] = fmaf(xv.z, w2.z, acc[i][2]);
            acc[i][2] = fmaf(xv.w, w3.z, acc[i][2]);
            acc[i][3] = fmaf(xv.x, w0.w, acc[i][3]);
            acc[i][3] = fmaf(xv.y, w1.w, acc[i][3]);
            acc[i][3] = fmaf(xv.z, w2.w, acc[i][3]);
            acc[i][3] = fmaf(xv.w, w3.w, acc[i][3]);
        }
    }

    float4 as4 = ((const float4*)as_)[cg];
    float4 ad4 = ((const float4*)ad_)[cg];
    #pragma unroll
    for (int i = 0; i < 4; ++i){
        int r = 4*rg + i;
        if (r < rows){
            int row = base + r;
            uint2 pk;
            pk.x = pack_bf2(acc[i][0], acc[i][1]);
            pk.y = pack_bf2(acc[i][2], acc[i][3]);
            ((uint2*)xp16)[(size_t)row * 32 + cg] = pk;
            float ps = acc[i][0]*as4.x + acc[i][1]*as4.y + acc[i][2]*as4.z + acc[i][3]*as4.w;
            float pd = acc[i][0]*ad4.x + acc[i][1]*ad4.y + acc[i][2]*ad4.z + acc[i][3]*ad4.w;
            ps += __shfl_xor(ps, 1); ps += __shfl_xor(ps, 2); ps += __shfl_xor(ps, 4);
            pd += __shfl_xor(pd, 1); pd += __shfl_xor(pd, 2); pd += __shfl_xor(pd, 4);
            if ((cg & 7) == 0){
                int h = cg >> 3;
                als[(size_t)row * 4 + h] = ps;
                ald[(size_t)row * 4 + h] = pd;
            }
        }
    }
}

// ---------------- per-node softmax aggregation: one WAVE per node, uint2 gather ----------------
// lane l: c = l&31 -> channels 4c..4c+3 (head h=c>>3); half = l>>5 handles edges 2j+half.
__global__ __launch_bounds__(256) void gat_agg3(
        const uint2* __restrict__ xp16, const float4* __restrict__ als,
        const float4* __restrict__ ald,
        const int* __restrict__ indptr, const int* __restrict__ srcs,
        const float* __restrict__ bias,
        float* __restrict__ hout, int N, int mode,
        const float* __restrict__ cW, const float* __restrict__ cb,
        float* __restrict__ fout){
    int wid = threadIdx.x >> 6;
    int l   = threadIdx.x & 63;
    int n = blockIdx.x * 4 + wid;
    __shared__ int   ssh[4][64];
    __shared__ float esh[4][64][4];
    if (n >= N) return;

    int beg = indptr[n], end = indptr[n + 1];
    float4 ad4 = ald[n];
    int c    = l & 31;
    int half = l >> 5;
    int h    = c >> 3;

    float m0 = -INFINITY, m1 = -INFINITY, m2 = -INFINITY, m3 = -INFINITY;
    float d0 = 0.f, d1 = 0.f, d2 = 0.f, d3 = 0.f;
    float4 acc = make_float4(0.f, 0.f, 0.f, 0.f);

    for (int cbeg = beg; cbeg < end; cbeg += 64){
        int cnt = end - cbeg; if (cnt > 64) cnt = 64;
        float e0 = -INFINITY, e1 = -INFINITY, e2 = -INFINITY, e3 = -INFINITY;
        if (l < cnt){
            int s = srcs[cbeg + l];
            ssh[wid][l] = s;
            float4 a4 = als[s];
            e0 = lrelu(a4.x + ad4.x);
            e1 = lrelu(a4.y + ad4.y);
            e2 = lrelu(a4.z + ad4.z);
            e3 = lrelu(a4.w + ad4.w);
        }
        float c0 = wmax(e0), c1 = wmax(e1), c2 = wmax(e2), c3 = wmax(e3);
        float nm0 = fmaxf(m0, c0), nm1 = fmaxf(m1, c1);
        float nm2 = fmaxf(m2, c2), nm3 = fmaxf(m3, c3);
        float r0 = __expf(m0 - nm0), r1 = __expf(m1 - nm1);
        float r2 = __expf(m2 - nm2), r3 = __expf(m3 - nm3);
        d0 *= r0; d1 *= r1; d2 *= r2; d3 *= r3;
        float rh = sel4(r0, r1, r2, r3, h);
        acc.x *= rh; acc.y *= rh; acc.z *= rh; acc.w *= rh;
        m0 = nm0; m1 = nm1; m2 = nm2; m3 = nm3;

        float p0 = 0.f, p1 = 0.f, p2 = 0.f, p3 = 0.f;
        if (l < cnt){
            p0 = __expf(e0 - m0);
            p1 = __expf(e1 - m1);
            p2 = __expf(e2 - m2);
            p3 = __expf(e3 - m3);
            *((float4*)&esh[wid][l][0]) = make_float4(p0, p1, p2, p3);
        }
        d0 += wsum(p0); d1 += wsum(p1); d2 += wsum(p2); d3 += wsum(p3);

        int pairs = cnt >> 1;
        int it = 0;
        for (; it + 2 <= pairs; it += 2){
            int ea = 2 * it + half;
            int eb = ea + 2;
            int sa = ssh[wid][ea]; float wa = esh[wid][ea][h];
            int sb = ssh[wid][eb]; float wb = esh[wid][eb][h];
            uint2 ua = xp16[(size_t)sa * 32 + c];
            uint2 ub = xp16[(size_t)sb * 32 + c];
            acc.x = fmaf(bflo(ua.x), wa, acc.x);
            acc.y = fmaf(bfhi(ua.x), wa, acc.y);
            acc.z = fmaf(bflo(ua.y), wa, acc.z);
            acc.w = fmaf(bfhi(ua.y), wa, acc.w);
            acc.x = fmaf(bflo(ub.x), wb, acc.x);
            acc.y = fmaf(bfhi(ub.x), wb, acc.y);
            acc.z = fmaf(bflo(ub.y), wb, acc.z);
            acc.w = fmaf(bfhi(ub.y), wb, acc.w);
        }
        for (; it < pairs; ++it){
            int e = 2 * it + half;
            int s = ssh[wid][e]; float w = esh[wid][e][h];
            uint2 u = xp16[(size_t)s * 32 + c];
            acc.x = fmaf(bflo(u.x), w, acc.x);
            acc.y = fmaf(bfhi(u.x), w, acc.y);
            acc.z = fmaf(bflo(u.y), w, acc.z);
            acc.w = fmaf(bfhi(u.y), w, acc.w);
        }
        if (cnt & 1){
            int e = cnt - 1;
            int s = ssh[wid][e];
            float w = (half == 0) ? esh[wid][e][h] : 0.f;
            uint2 u = xp16[(size_t)s * 32 + c];
            acc.x = fmaf(bflo(u.x), w, acc.x);
            acc.y = fmaf(bfhi(u.x), w, acc.y);
            acc.z = fmaf(bflo(u.y), w, acc.z);
            acc.w = fmaf(bfhi(u.y), w, acc.w);
        }
    }

    // cross-half combine: both halves end with full sums
    acc.x += __shfl_xor(acc.x, 32);
    acc.y += __shfl_xor(acc.y, 32);
    acc.z += __shfl_xor(acc.z, 32);
    acc.w += __shfl_xor(acc.w, 32);

    float dh = sel4(d0, d1, d2, d3, h);
    float inv = 1.f / (dh + 1e-16f);
    float4 b4 = ((const float4*)bias)[c];
    float4 v;
    v.x = acc.x * inv + b4.x;
    v.y = acc.y * inv + b4.y;
    v.z = acc.z * inv + b4.z;
    v.w = acc.w * inv + b4.w;
    v.x = v.x > 0.f ? v.x : (__expf(v.x) - 1.f);
    v.y = v.y > 0.f ? v.y : (__expf(v.y) - 1.f);
    v.z = v.z > 0.f ? v.z : (__expf(v.z) - 1.f);
    v.w = v.w > 0.f ? v.w : (__expf(v.w) - 1.f);

    if (mode == 0){
        if (half == 0) ((float4*)hout)[(size_t)n * 32 + c] = v;
    } else {
        float p = 0.f;
        if (half == 0){
            float4 cw4 = ((const float4*)cW)[c];
            p = v.x * cw4.x + v.y * cw4.y + v.z * cw4.z + v.w * cw4.w;
        }
        p = wsum(p);
        if (l == 0){
            float logit = p + cb[0];
            fout[n] = 1.f / (1.f + __expf(-logit));
        }
    }
}

extern "C" void kernel_launch(void* const* d_in, const int* in_sizes, int n_in,
                              void* d_out, int out_size, void* d_ws, size_t ws_size,
                              hipStream_t stream){
    const float* x   = (const float*)d_in[0];
    const int*   ei  = (const int*)d_in[1];
    const float* W1  = (const float*)d_in[2];
    const float* as1 = (const float*)d_in[3];
    const float* ad1 = (const float*)d_in[4];
    const float* b1  = (const float*)d_in[5];
    const float* W2  = (const float*)d_in[6];
    const float* as2 = (const float*)d_in[7];
    const float* ad2 = (const float*)d_in[8];
    const float* b2  = (const float*)d_in[9];
    const float* W3  = (const float*)d_in[10];
    const float* as3 = (const float*)d_in[11];
    const float* ad3 = (const float*)d_in[12];
    const float* b3  = (const float*)d_in[13];
    const float* cW  = (const float*)d_in[14];
    const float* cb  = (const float*)d_in[15];
    float* out = (float*)d_out;

    int N = in_sizes[0] / 3;
    int E = in_sizes[1] / 2;
    int EN = E + N;
    int NBK = (N + BK_NODES - 1) / BK_NODES;

    char* ws = (char*)d_ws;
    size_t off = 0;
    auto alloc = [&](size_t bytes) -> void* {
        void* p = ws + off;
        off += (bytes + 255) & ~(size_t)255;
        return p;
    };
    int*    deg     = (int*)alloc((size_t)N * 4);
    int*    indptr  = (int*)alloc((size_t)(N + 1) * 4);
    int*    srcs    = (int*)alloc((size_t)EN * 4);
    uint_t* pairbuf = (uint_t*)alloc((size_t)EN * 4);
    uint_t* XP      = (uint_t*)alloc((size_t)N * 64 * 4);
    float*  H       = (float*)alloc((size_t)N * 128 * 4);
    float*  ALS     = (float*)alloc((size_t)N * 4 * 4);
    float*  ALD     = (float*)alloc((size_t)N * 4 * 4);
    int*    bsum    = (int*)alloc((size_t)1024 * 4);
    int*    gcursor = (int*)alloc((size_t)MAXBK * 4);
    (void)ws_size;

    int NB = (N + 1023) / 1024;

    hipMemsetAsync(deg, 0, (size_t)N * 4, stream);
    hist_kernel<<<(EN + 255) / 256, 256, 0, stream>>>(ei, E, N, deg);
    scan_blocksum<<<NB, 256, 0, stream>>>(deg, bsum, N);
    scan_partials<<<1, 1024, 0, stream>>>(bsum, NB, indptr, N);
    scan_final<<<NB, 256, 0, stream>>>(deg, bsum, indptr, gcursor, N);
    partition_kernel<<<(EN + PART_CHUNK - 1) / PART_CHUNK, 256, 0, stream>>>(
        ei, E, N, gcursor, pairbuf, NBK);
    bucket_sort_kernel<<<NBK, 256, 0, stream>>>(pairbuf, indptr, srcs, N, NBK);

    int ab = (N + 3) / 4;
    // layer 1 (K=3)
    linear_al<<<(N + 7) / 8, 128, 0, stream>>>(x, W1, as1, ad1, XP, ALS, ALD, N, 3);
    gat_agg3<<<ab, 256, 0, stream>>>((const uint2*)XP, (const float4*)ALS, (const float4*)ALD,
                                     indptr, srcs, b1, H, N, 0, nullptr, nullptr, nullptr);
    // layer 2
    gemm128_al<<<(N + 31) / 32, 256, 0, stream>>>(H, W2, as2, ad2, XP, ALS, ALD, N);
    gat_agg3<<<ab, 256, 0, stream>>>((const uint2*)XP, (const float4*)ALS, (const float4*)ALD,
                                     indptr, srcs, b2, H, N, 0, nullptr, nullptr, nullptr);
    // layer 3 + fused classifier
    gemm128_al<<<(N + 31) / 32, 256, 0, stream>>>(H, W3, as3, ad3, XP, ALS, ALD, N);
    gat_agg3<<<ab, 256, 0, stream>>>((const uint2*)XP, (const float4*)ALS, (const float4*)ALD,
                                     indptr, srcs, b3, nullptr, N, 1, cW, cb, out);
}

// Round 7
// 322.563 us; speedup vs baseline: 1.1431x; 1.1431x over previous
//
#include <hip/hip_runtime.h>
#include <math.h>

typedef unsigned int uint_t;

#define BK_SHIFT 7
#define BK_NODES 128
#define MAXBK 512          // supports N <= 65536
#define PART_CHUNK 4096
#define SORT_CAP 4096

__device__ __forceinline__ float lrelu(float x){ return x > 0.f ? x : 0.2f*x; }
__device__ __forceinline__ float sel4(float a, float b, float c, float d, int h){
    return h==0 ? a : (h==1 ? b : (h==2 ? c : d));
}
__device__ __forceinline__ float wsum(float v){
    #pragma unroll
    for (int m = 1; m < 64; m <<= 1) v += __shfl_xor(v, m);
    return v;
}
__device__ __forceinline__ uint_t pack_bf2(float a, float b){
    uint_t ua = __float_as_uint(a); uint_t ub = __float_as_uint(b);
    ua += 0x7FFFu + ((ua >> 16) & 1u);
    ub += 0x7FFFu + ((ub >> 16) & 1u);
    return (ua >> 16) | (ub & 0xFFFF0000u);
}
__device__ __forceinline__ float bflo(uint_t u){ return __uint_as_float(u << 16); }
__device__ __forceinline__ float bfhi(uint_t u){ return __uint_as_float(u & 0xFFFF0000u); }

// ---------------- CSR build ----------------

__global__ void hist_kernel(const int* __restrict__ ei, int E, int N, int* __restrict__ deg){
    int idx = blockIdx.x * blockDim.x + threadIdx.x;
    if (idx >= E + N) return;
    int d = (idx < E) ? ei[E + idx] : (idx - E);
    atomicAdd(&deg[d], 1);
}

__global__ __launch_bounds__(256) void scan_blocksum(const int* __restrict__ deg,
                                                     int* __restrict__ bsum, int N){
    int b = blockIdx.x, t = threadIdx.x;
    int base = b * 1024 + t * 4;
    int s = 0;
    #pragma unroll
    for (int i = 0; i < 4; ++i){ int idx = base + i; if (idx < N) s += deg[idx]; }
    __shared__ int sm[256];
    sm[t] = s; __syncthreads();
    for (int off = 128; off > 0; off >>= 1){
        if (t < off) sm[t] += sm[t + off];
        __syncthreads();
    }
    if (t == 0) bsum[b] = sm[0];
}

__global__ __launch_bounds__(1024) void scan_partials(int* __restrict__ bsum, int NB,
                                                      int* __restrict__ indptr, int N){
    int t = threadIdx.x;
    int v = (t < NB) ? bsum[t] : 0;
    __shared__ int sm[1024];
    sm[t] = v; __syncthreads();
    for (int off = 1; off < 1024; off <<= 1){
        int u = (t >= off) ? sm[t - off] : 0;
        __syncthreads();
        sm[t] += u;
        __syncthreads();
    }
    if (t < NB) bsum[t] = (t == 0) ? 0 : sm[t - 1];
    if (t == NB - 1) indptr[N] = sm[t];
}

// also seeds gcursor[b] = indptr[b*128]
__global__ __launch_bounds__(256) void scan_final(const int* __restrict__ deg,
                                                  const int* __restrict__ bsum,
                                                  int* __restrict__ indptr,
                                                  int* __restrict__ gcursor, int N){
    int b = blockIdx.x, t = threadIdx.x;
    int base = b * 1024 + t * 4;
    int v0 = 0, v1 = 0, v2 = 0, v3 = 0;
    if (base + 0 < N) v0 = deg[base + 0];
    if (base + 1 < N) v1 = deg[base + 1];
    if (base + 2 < N) v2 = deg[base + 2];
    if (base + 3 < N) v3 = deg[base + 3];
    int s = v0 + v1 + v2 + v3;
    __shared__ int sm[256];
    sm[t] = s; __syncthreads();
    for (int off = 1; off < 256; off <<= 1){
        int u = (t >= off) ? sm[t - off] : 0;
        __syncthreads();
        sm[t] += u;
        __syncthreads();
    }
    int run = bsum[b] + ((t == 0) ? 0 : sm[t - 1]);
    #pragma unroll
    for (int i = 0; i < 4; ++i){
        int idx = base + i;
        int v = (i == 0) ? v0 : (i == 1) ? v1 : (i == 2) ? v2 : v3;
        if (idx < N){
            indptr[idx] = run;
            if ((idx & (BK_NODES - 1)) == 0) gcursor[idx >> BK_SHIFT] = run;
            run += v;
        }
    }
}

// phase A: partition packed (src | dlow<<25) into bucket-contiguous pairbuf
__global__ __launch_bounds__(256) void partition_kernel(
        const int* __restrict__ ei, int E, int N,
        int* __restrict__ gcursor, uint_t* __restrict__ pairbuf, int NBK){
    __shared__ int hist[MAXBK];
    __shared__ int sA[MAXBK];
    __shared__ int sB[MAXBK];
    __shared__ int destadj[MAXBK];
    __shared__ int cnt2[MAXBK];
    __shared__ uint_t staged[PART_CHUNK];
    int t = threadIdx.x;
    int base = blockIdx.x * PART_CHUNK;
    int total = E + N;
    int cnt = total - base; if (cnt > PART_CHUNK) cnt = PART_CHUNK; if (cnt < 0) cnt = 0;

    for (int i = t; i < MAXBK; i += 256){ hist[i] = 0; cnt2[i] = 0; }
    __syncthreads();
    for (int i = t; i < cnt; i += 256){
        int idx = base + i;
        int d = (idx < E) ? ei[E + idx] : (idx - E);
        atomicAdd(&hist[d >> BK_SHIFT], 1);
    }
    __syncthreads();
    sA[t] = hist[t]; sA[t + 256] = hist[t + 256];
    __syncthreads();
    int* psrc = sA; int* pdst = sB;
    for (int off = 1; off < MAXBK; off <<= 1){
        int i0 = t, i1 = t + 256;
        pdst[i0] = psrc[i0] + ((i0 >= off) ? psrc[i0 - off] : 0);
        pdst[i1] = psrc[i1] + ((i1 >= off) ? psrc[i1 - off] : 0);
        __syncthreads();
        int* tmp = psrc; psrc = pdst; pdst = tmp;
    }
    for (int b = t; b < NBK; b += 256){
        int c = hist[b];
        int gstart = (b == 0) ? 0 : psrc[b - 1];
        int rbase = c > 0 ? atomicAdd(&gcursor[b], c) : 0;
        destadj[b] = rbase - gstart;
        cnt2[b] = gstart;
    }
    __syncthreads();
    for (int i = t; i < cnt; i += 256){
        int idx = base + i;
        int d, s;
        if (idx < E){ s = ei[idx]; d = ei[E + idx]; }
        else        { s = d = idx - E; }
        int b = d >> BK_SHIFT;
        int pos = atomicAdd(&cnt2[b], 1);
        staged[pos] = (uint_t)s | ((uint_t)(d & (BK_NODES - 1)) << 25);
    }
    __syncthreads();
    for (int p = t; p < cnt; p += 256){
        uint_t pr = staged[p];
        int lo = 0, hi = NBK - 1;
        while (lo < hi){
            int mid = (lo + hi) >> 1;
            if (p < psrc[mid]) hi = mid; else lo = mid + 1;
        }
        pairbuf[destadj[lo] + p] = pr;
    }
}

// phase B: per-bucket counting sort into final CSR srcs
__global__ __launch_bounds__(256) void bucket_sort_kernel(
        const uint_t* __restrict__ pairbuf, const int* __restrict__ indptr,
        int* __restrict__ srcs, int N, int NBK){
    int b = blockIdx.x;
    int nb = b << BK_SHIFT;
    int nend = nb + BK_NODES; if (nend > N) nend = N;
    int beg = indptr[nb], end = indptr[nend];
    int cnt = end - beg;
    __shared__ int lptr[BK_NODES];
    __shared__ int outb[SORT_CAP];
    int t = threadIdx.x;
    if (t < BK_NODES){
        int node = nb + t;
        lptr[t] = (node < N) ? (indptr[node] - beg) : 0;
    }
    __syncthreads();
    if (cnt <= SORT_CAP){
        for (int i = t; i < cnt; i += 256){
            uint_t pr = pairbuf[beg + i];
            int pos = atomicAdd(&lptr[(int)(pr >> 25)], 1);
            outb[pos] = (int)(pr & 0x1FFFFFFu);
        }
        __syncthreads();
        for (int i = t; i < cnt; i += 256) srcs[beg + i] = outb[i];
    } else {
        for (int i = t; i < cnt; i += 256){
            uint_t pr = pairbuf[beg + i];
            int pos = atomicAdd(&lptr[(int)(pr >> 25)], 1);
            srcs[beg + pos] = (int)(pr & 0x1FFFFFFu);
        }
    }
}

// ---------------- layer-1 linear (K=3): xp packed bf16x2 ----------------
__global__ __launch_bounds__(128) void linear_al(
        const float* __restrict__ in, const float* __restrict__ W,
        const float* __restrict__ as_, const float* __restrict__ ad_,
        uint_t* __restrict__ xp16, float* __restrict__ als, float* __restrict__ ald,
        int N, int K){
    __shared__ float hs[8 * 3];
    int t = threadIdx.x;
    int base = blockIdx.x * 8;
    int rows = N - base; if (rows > 8) rows = 8;
    for (int idx = t; idx < rows * K; idx += 128){
        int r = idx / K, k = idx - r * K;
        hs[r * K + k] = in[(size_t)(base + r) * K + k];
    }
    __syncthreads();
    float acc[8] = {0.f,0.f,0.f,0.f,0.f,0.f,0.f,0.f};
    for (int k = 0; k < K; ++k){
        float w = W[k * 128 + t];
        #pragma unroll
        for (int r = 0; r < 8; ++r) acc[r] += hs[r * K + k] * w;
    }
    float asv = as_[t], adv = ad_[t];
    for (int r = 0; r < rows; ++r){
        int row = base + r;
        float v = acc[r];
        float vo = __shfl_xor(v, 1);
        if (!(t & 1)) xp16[(size_t)row * 64 + (t >> 1)] = pack_bf2(v, vo);
        float vs = v * asv, vd = v * adv;
        #pragma unroll
        for (int m = 16; m >= 1; m >>= 1){
            vs += __shfl_xor(vs, m);
            vd += __shfl_xor(vd, m);
        }
        if ((t & 31) == 0){
            int h = t >> 5;
            als[row * 4 + h] = vs;
            ald[row * 4 + h] = vd;
        }
    }
}

// ---------------- K=128 linear: register-tiled fp32 GEMM + fused als/ald ----------------
__global__ __launch_bounds__(256) void gemm128_al(
        const float* __restrict__ in, const float* __restrict__ W,
        const float* __restrict__ as_, const float* __restrict__ ad_,
        uint_t* __restrict__ xp16, float* __restrict__ als, float* __restrict__ ald,
        int N){
    __shared__ float Xs[32][128];
    int t = threadIdx.x;
    int base = blockIdx.x * 32;
    int rows = N - base; if (rows > 32) rows = 32;
    for (int f = t; f < 1024; f += 256){
        int r = f >> 5, q = f & 31;
        float4 v = (r < rows) ? ((const float4*)(in + (size_t)(base + r) * 128))[q]
                              : make_float4(0.f,0.f,0.f,0.f);
        ((float4*)Xs)[f] = v;
    }
    __syncthreads();
    int cg = t & 31;
    int rg = t >> 5;
    float acc[4][4];
    #pragma unroll
    for (int i = 0; i < 4; ++i)
        #pragma unroll
        for (int j = 0; j < 4; ++j) acc[i][j] = 0.f;

    const float4* W4 = (const float4*)W;
    for (int k4 = 0; k4 < 32; ++k4){
        float4 w0 = W4[(4*k4+0)*32 + cg];
        float4 w1 = W4[(4*k4+1)*32 + cg];
        float4 w2 = W4[(4*k4+2)*32 + cg];
        float4 w3 = W4[(4*k4+3)*32 + cg];
        #pragma unroll
        for (int i = 0; i < 4; ++i){
            float4 xv = ((const float4*)(&Xs[4*rg + i][0]))[k4];
            acc[i][0] = fmaf(xv.x, w0.x, acc[i][0]);
            acc[i][0] = fmaf(xv.y, w1.x, acc[i][0]);
            acc[i][0] = fmaf(xv.z, w2.x, acc[i][0]);
            acc[i][0] = fmaf(xv.w, w3.x, acc[i][0]);
            acc[i][1] = fmaf(xv.x, w0.y, acc[i][1]);
            acc[i][1] = fmaf(xv.y, w1.y, acc[i][1]);
            acc[i][1] = fmaf(xv.z, w2.y, acc[i][1]);
            acc[i][1] = fmaf(xv.w, w3.y, acc[i][1]);
            acc[i][2] = fmaf(xv.x, w0.z, acc[i][2]);
            acc[i][2] = fmaf(xv.y, w1.z, acc[i][2]);
            acc[i][2] = fmaf(xv.z, w2.z, acc[i][2]);
            acc[i][2] = fmaf(xv.w, w3.z, acc[i][2]);
            acc[i][3] = fmaf(xv.x, w0.w, acc[i][3]);
            acc[i][3] = fmaf(xv.y, w1.w, acc[i][3]);
            acc[i][3] = fmaf(xv.z, w2.w, acc[i][3]);
            acc[i][3] = fmaf(xv.w, w3.w, acc[i][3]);
        }
    }

    float4 as4 = ((const float4*)as_)[cg];
    float4 ad4 = ((const float4*)ad_)[cg];
    #pragma unroll
    for (int i = 0; i < 4; ++i){
        int r = 4*rg + i;
        if (r < rows){
            int row = base + r;
            uint2 pk;
            pk.x = pack_bf2(acc[i][0], acc[i][1]);
            pk.y = pack_bf2(acc[i][2], acc[i][3]);
            ((uint2*)xp16)[(size_t)row * 32 + cg] = pk;
            float ps = acc[i][0]*as4.x + acc[i][1]*as4.y + acc[i][2]*as4.z + acc[i][3]*as4.w;
            float pd = acc[i][0]*ad4.x + acc[i][1]*ad4.y + acc[i][2]*ad4.z + acc[i][3]*ad4.w;
            ps += __shfl_xor(ps, 1); ps += __shfl_xor(ps, 2); ps += __shfl_xor(ps, 4);
            pd += __shfl_xor(pd, 1); pd += __shfl_xor(pd, 2); pd += __shfl_xor(pd, 4);
            if ((cg & 7) == 0){
                int h = cg >> 3;
                als[(size_t)row * 4 + h] = ps;
                ald[(size_t)row * 4 + h] = pd;
            }
        }
    }
}

// ---------------- per-node softmax aggregation: one WAVE per node ----------------
// agg2 layout (lane l owns channels 2l,2l+1; head h=l>>4), NO max-subtraction
// (exp(e)/sum(exp(e)) is exact; |e| <~ 5 here so no overflow), gather unroll x8.
__global__ __launch_bounds__(256) void gat_agg4(
        const uint_t* __restrict__ xp16, const float4* __restrict__ als,
        const float4* __restrict__ ald,
        const int* __restrict__ indptr, const int* __restrict__ srcs,
        const float* __restrict__ bias,
        float* __restrict__ hout, int N, int mode,
        const float* __restrict__ cW, const float* __restrict__ cb,
        float* __restrict__ fout){
    int wid = threadIdx.x >> 6;
    int l   = threadIdx.x & 63;
    int n = blockIdx.x * 4 + wid;
    __shared__ int   ssh[4][64];
    __shared__ float esh[4][64][4];
    if (n >= N) return;

    int beg = indptr[n], end = indptr[n + 1];
    float4 ad4 = ald[n];
    int h = l >> 4;

    float d0 = 0.f, d1 = 0.f, d2 = 0.f, d3 = 0.f;
    float ax = 0.f, ay = 0.f;

    for (int cbeg = beg; cbeg < end; cbeg += 64){
        int cnt = end - cbeg; if (cnt > 64) cnt = 64;
        float p0 = 0.f, p1 = 0.f, p2 = 0.f, p3 = 0.f;
        if (l < cnt){
            int s = srcs[cbeg + l];
            ssh[wid][l] = s;
            float4 a4 = als[s];
            p0 = __expf(lrelu(a4.x + ad4.x));
            p1 = __expf(lrelu(a4.y + ad4.y));
            p2 = __expf(lrelu(a4.z + ad4.z));
            p3 = __expf(lrelu(a4.w + ad4.w));
            *((float4*)&esh[wid][l][0]) = make_float4(p0, p1, p2, p3);
        }
        d0 += wsum(p0); d1 += wsum(p1); d2 += wsum(p2); d3 += wsum(p3);

        int j = 0;
        for (; j + 8 <= cnt; j += 8){
            int s0 = ssh[wid][j+0]; float w0 = esh[wid][j+0][h];
            int s1 = ssh[wid][j+1]; float w1 = esh[wid][j+1][h];
            int s2 = ssh[wid][j+2]; float w2 = esh[wid][j+2][h];
            int s3 = ssh[wid][j+3]; float w3 = esh[wid][j+3][h];
            int s4 = ssh[wid][j+4]; float w4 = esh[wid][j+4][h];
            int s5 = ssh[wid][j+5]; float w5 = esh[wid][j+5][h];
            int s6 = ssh[wid][j+6]; float w6 = esh[wid][j+6][h];
            int s7 = ssh[wid][j+7]; float w7 = esh[wid][j+7][h];
            uint_t u0 = xp16[(size_t)s0 * 64 + l];
            uint_t u1 = xp16[(size_t)s1 * 64 + l];
            uint_t u2 = xp16[(size_t)s2 * 64 + l];
            uint_t u3 = xp16[(size_t)s3 * 64 + l];
            uint_t u4 = xp16[(size_t)s4 * 64 + l];
            uint_t u5 = xp16[(size_t)s5 * 64 + l];
            uint_t u6 = xp16[(size_t)s6 * 64 + l];
            uint_t u7 = xp16[(size_t)s7 * 64 + l];
            ax = fmaf(bflo(u0), w0, ax); ay = fmaf(bfhi(u0), w0, ay);
            ax = fmaf(bflo(u1), w1, ax); ay = fmaf(bfhi(u1), w1, ay);
            ax = fmaf(bflo(u2), w2, ax); ay = fmaf(bfhi(u2), w2, ay);
            ax = fmaf(bflo(u3), w3, ax); ay = fmaf(bfhi(u3), w3, ay);
            ax = fmaf(bflo(u4), w4, ax); ay = fmaf(bfhi(u4), w4, ay);
            ax = fmaf(bflo(u5), w5, ax); ay = fmaf(bfhi(u5), w5, ay);
            ax = fmaf(bflo(u6), w6, ax); ay = fmaf(bfhi(u6), w6, ay);
            ax = fmaf(bflo(u7), w7, ax); ay = fmaf(bfhi(u7), w7, ay);
        }
        for (; j < cnt; ++j){
            int s = ssh[wid][j];
            float w = esh[wid][j][h];
            uint_t u = xp16[(size_t)s * 64 + l];
            ax = fmaf(bflo(u), w, ax);
            ay = fmaf(bfhi(u), w, ay);
        }
    }

    float dh = sel4(d0, d1, d2, d3, h);
    float inv = 1.f / (dh + 1e-16f);
    float2 b2 = ((const float2*)bias)[l];
    float vx = ax * inv + b2.x;
    float vy = ay * inv + b2.y;
    vx = vx > 0.f ? vx : (__expf(vx) - 1.f);
    vy = vy > 0.f ? vy : (__expf(vy) - 1.f);

    if (mode == 0){
        ((float2*)hout)[(size_t)n * 64 + l] = make_float2(vx, vy);
    } else {
        float2 cw2 = ((const float2*)cW)[l];
        float p = vx * cw2.x + vy * cw2.y;
        p = wsum(p);
        if (l == 0){
            float logit = p + cb[0];
            fout[n] = 1.f / (1.f + __expf(-logit));
        }
    }
}

extern "C" void kernel_launch(void* const* d_in, const int* in_sizes, int n_in,
                              void* d_out, int out_size, void* d_ws, size_t ws_size,
                              hipStream_t stream){
    const float* x   = (const float*)d_in[0];
    const int*   ei  = (const int*)d_in[1];
    const float* W1  = (const float*)d_in[2];
    const float* as1 = (const float*)d_in[3];
    const float* ad1 = (const float*)d_in[4];
    const float* b1  = (const float*)d_in[5];
    const float* W2  = (const float*)d_in[6];
    const float* as2 = (const float*)d_in[7];
    const float* ad2 = (const float*)d_in[8];
    const float* b2  = (const float*)d_in[9];
    const float* W3  = (const float*)d_in[10];
    const float* as3 = (const float*)d_in[11];
    const float* ad3 = (const float*)d_in[12];
    const float* b3  = (const float*)d_in[13];
    const float* cW  = (const float*)d_in[14];
    const float* cb  = (const float*)d_in[15];
    float* out = (float*)d_out;

    int N = in_sizes[0] / 3;
    int E = in_sizes[1] / 2;
    int EN = E + N;
    int NBK = (N + BK_NODES - 1) / BK_NODES;

    char* ws = (char*)d_ws;
    size_t off = 0;
    auto alloc = [&](size_t bytes) -> void* {
        void* p = ws + off;
        off += (bytes + 255) & ~(size_t)255;
        return p;
    };
    int*    deg     = (int*)alloc((size_t)N * 4);
    int*    indptr  = (int*)alloc((size_t)(N + 1) * 4);
    int*    srcs    = (int*)alloc((size_t)EN * 4);
    uint_t* pairbuf = (uint_t*)alloc((size_t)EN * 4);
    uint_t* XP      = (uint_t*)alloc((size_t)N * 64 * 4);
    float*  H       = (float*)alloc((size_t)N * 128 * 4);
    float*  ALS     = (float*)alloc((size_t)N * 4 * 4);
    float*  ALD     = (float*)alloc((size_t)N * 4 * 4);
    int*    bsum    = (int*)alloc((size_t)1024 * 4);
    int*    gcursor = (int*)alloc((size_t)MAXBK * 4);
    (void)ws_size;

    int NB = (N + 1023) / 1024;

    hipMemsetAsync(deg, 0, (size_t)N * 4, stream);
    hist_kernel<<<(EN + 255) / 256, 256, 0, stream>>>(ei, E, N, deg);
    scan_blocksum<<<NB, 256, 0, stream>>>(deg, bsum, N);
    scan_partials<<<1, 1024, 0, stream>>>(bsum, NB, indptr, N);
    scan_final<<<NB, 256, 0, stream>>>(deg, bsum, indptr, gcursor, N);
    partition_kernel<<<(EN + PART_CHUNK - 1) / PART_CHUNK, 256, 0, stream>>>(
        ei, E, N, gcursor, pairbuf, NBK);
    bucket_sort_kernel<<<NBK, 256, 0, stream>>>(pairbuf, indptr, srcs, N, NBK);

    int ab = (N + 3) / 4;
    // layer 1 (K=3)
    linear_al<<<(N + 7) / 8, 128, 0, stream>>>(x, W1, as1, ad1, XP, ALS, ALD, N, 3);
    gat_agg4<<<ab, 256, 0, stream>>>(XP, (const float4*)ALS, (const float4*)ALD,
                                     indptr, srcs, b1, H, N, 0, nullptr, nullptr, nullptr);
    // layer 2
    gemm128_al<<<(N + 31) / 32, 256, 0, stream>>>(H, W2, as2, ad2, XP, ALS, ALD, N);
    gat_agg4<<<ab, 256, 0, stream>>>(XP, (const float4*)ALS, (const float4*)ALD,
                                     indptr, srcs, b2, H, N, 0, nullptr, nullptr, nullptr);
    // layer 3 + fused classifier
    gemm128_al<<<(N + 31) / 32, 256, 0, stream>>>(H, W3, as3, ad3, XP, ALS, ALD, N);
    gat_agg4<<<ab, 256, 0, stream>>>(XP, (const float4*)ALS, (const float4*)ALD,
                                     indptr, srcs, b3, nullptr, N, 1, cW, cb, out);
}

// Round 8
// 262.338 us; speedup vs baseline: 1.4056x; 1.2296x over previous
//
#include <hip/hip_runtime.h>
#include <math.h>

typedef unsigned int uint_t;
typedef __attribute__((ext_vector_type(8))) short bf16x8;
typedef __attribute__((ext_vector_type(4))) float f32x4;

#define BK_SHIFT 7
#define BK_NODES 128
#define MAXBK 512          // supports N <= 65536
#define PART_CHUNK 4096
#define SORT_CAP 4096

__device__ __forceinline__ float lrelu(float x){ return x > 0.f ? x : 0.2f*x; }
__device__ __forceinline__ float sel4(float a, float b, float c, float d, int h){
    return h==0 ? a : (h==1 ? b : (h==2 ? c : d));
}
__device__ __forceinline__ float wsum(float v){
    #pragma unroll
    for (int m = 1; m < 64; m <<= 1) v += __shfl_xor(v, m);
    return v;
}
__device__ __forceinline__ uint_t pack_bf2(float a, float b){
    uint_t ua = __float_as_uint(a); uint_t ub = __float_as_uint(b);
    ua += 0x7FFFu + ((ua >> 16) & 1u);
    ub += 0x7FFFu + ((ub >> 16) & 1u);
    return (ua >> 16) | (ub & 0xFFFF0000u);
}
__device__ __forceinline__ float bflo(uint_t u){ return __uint_as_float(u << 16); }
__device__ __forceinline__ float bfhi(uint_t u){ return __uint_as_float(u & 0xFFFF0000u); }
__device__ __forceinline__ bf16x8 mk_bf8(uint4 u){
    bf16x8 r;
    r[0]=(short)(u.x & 0xFFFFu); r[1]=(short)(u.x >> 16);
    r[2]=(short)(u.y & 0xFFFFu); r[3]=(short)(u.y >> 16);
    r[4]=(short)(u.z & 0xFFFFu); r[5]=(short)(u.z >> 16);
    r[6]=(short)(u.w & 0xFFFFu); r[7]=(short)(u.w >> 16);
    return r;
}

// ---------------- CSR build ----------------

__global__ void hist_kernel(const int* __restrict__ ei, int E, int N, int* __restrict__ deg){
    int idx = blockIdx.x * blockDim.x + threadIdx.x;
    if (idx >= E + N) return;
    int d = (idx < E) ? ei[E + idx] : (idx - E);
    atomicAdd(&deg[d], 1);
}

__global__ __launch_bounds__(256) void scan_blocksum(const int* __restrict__ deg,
                                                     int* __restrict__ bsum, int N){
    int b = blockIdx.x, t = threadIdx.x;
    int base = b * 1024 + t * 4;
    int s = 0;
    #pragma unroll
    for (int i = 0; i < 4; ++i){ int idx = base + i; if (idx < N) s += deg[idx]; }
    __shared__ int sm[256];
    sm[t] = s; __syncthreads();
    for (int off = 128; off > 0; off >>= 1){
        if (t < off) sm[t] += sm[t + off];
        __syncthreads();
    }
    if (t == 0) bsum[b] = sm[0];
}

__global__ __launch_bounds__(1024) void scan_partials(int* __restrict__ bsum, int NB,
                                                      int* __restrict__ indptr, int N){
    int t = threadIdx.x;
    int v = (t < NB) ? bsum[t] : 0;
    __shared__ int sm[1024];
    sm[t] = v; __syncthreads();
    for (int off = 1; off < 1024; off <<= 1){
        int u = (t >= off) ? sm[t - off] : 0;
        __syncthreads();
        sm[t] += u;
        __syncthreads();
    }
    if (t < NB) bsum[t] = (t == 0) ? 0 : sm[t - 1];
    if (t == NB - 1) indptr[N] = sm[t];
}

// also seeds gcursor[b] = indptr[b*128]
__global__ __launch_bounds__(256) void scan_final(const int* __restrict__ deg,
                                                  const int* __restrict__ bsum,
                                                  int* __restrict__ indptr,
                                                  int* __restrict__ gcursor, int N){
    int b = blockIdx.x, t = threadIdx.x;
    int base = b * 1024 + t * 4;
    int v0 = 0, v1 = 0, v2 = 0, v3 = 0;
    if (base + 0 < N) v0 = deg[base + 0];
    if (base + 1 < N) v1 = deg[base + 1];
    if (base + 2 < N) v2 = deg[base + 2];
    if (base + 3 < N) v3 = deg[base + 3];
    int s = v0 + v1 + v2 + v3;
    __shared__ int sm[256];
    sm[t] = s; __syncthreads();
    for (int off = 1; off < 256; off <<= 1){
        int u = (t >= off) ? sm[t - off] : 0;
        __syncthreads();
        sm[t] += u;
        __syncthreads();
    }
    int run = bsum[b] + ((t == 0) ? 0 : sm[t - 1]);
    #pragma unroll
    for (int i = 0; i < 4; ++i){
        int idx = base + i;
        int v = (i == 0) ? v0 : (i == 1) ? v1 : (i == 2) ? v2 : v3;
        if (idx < N){
            indptr[idx] = run;
            if ((idx & (BK_NODES - 1)) == 0) gcursor[idx >> BK_SHIFT] = run;
            run += v;
        }
    }
}

// phase A: partition packed (src | dlow<<25) into bucket-contiguous pairbuf
__global__ __launch_bounds__(256) void partition_kernel(
        const int* __restrict__ ei, int E, int N,
        int* __restrict__ gcursor, uint_t* __restrict__ pairbuf, int NBK){
    __shared__ int hist[MAXBK];
    __shared__ int sA[MAXBK];
    __shared__ int destadj[MAXBK];
    __shared__ int cnt2[MAXBK];
    __shared__ uint_t staged[PART_CHUNK];
    __shared__ unsigned short sbk[PART_CHUNK];
    int t = threadIdx.x;
    int base = blockIdx.x * PART_CHUNK;
    int total = E + N;
    int cnt = total - base; if (cnt > PART_CHUNK) cnt = PART_CHUNK; if (cnt < 0) cnt = 0;

    for (int i = t; i < MAXBK; i += 256){ hist[i] = 0; cnt2[i] = 0; }
    __syncthreads();
    for (int i = t; i < cnt; i += 256){
        int idx = base + i;
        int d = (idx < E) ? ei[E + idx] : (idx - E);
        atomicAdd(&hist[d >> BK_SHIFT], 1);
    }
    __syncthreads();
    // inclusive scan of hist into sA (single pass, serial-ish per thread pair ok at 512)
    sA[t] = hist[t]; sA[t + 256] = hist[t + 256];
    __syncthreads();
    // Hillis-Steele in place with ping-pong via registers per step
    for (int off = 1; off < MAXBK; off <<= 1){
        int i0 = t, i1 = t + 256;
        int a0 = sA[i0] + ((i0 >= off) ? sA[i0 - off] : 0);
        int a1 = sA[i1] + ((i1 >= off) ? sA[i1 - off] : 0);
        __syncthreads();
        sA[i0] = a0; sA[i1] = a1;
        __syncthreads();
    }
    for (int b = t; b < NBK; b += 256){
        int c = hist[b];
        int gstart = (b == 0) ? 0 : sA[b - 1];
        int rbase = c > 0 ? atomicAdd(&gcursor[b], c) : 0;
        destadj[b] = rbase - gstart;
        cnt2[b] = gstart;
    }
    __syncthreads();
    for (int i = t; i < cnt; i += 256){
        int idx = base + i;
        int d, s;
        if (idx < E){ s = ei[idx]; d = ei[E + idx]; }
        else        { s = d = idx - E; }
        int b = d >> BK_SHIFT;
        int pos = atomicAdd(&cnt2[b], 1);
        staged[pos] = (uint_t)s | ((uint_t)(d & (BK_NODES - 1)) << 25);
        sbk[pos] = (unsigned short)b;
    }
    __syncthreads();
    for (int p = t; p < cnt; p += 256){
        int b = (int)sbk[p];
        pairbuf[destadj[b] + p] = staged[p];
    }
}

// phase B: per-bucket counting sort into final CSR srcs
__global__ __launch_bounds__(256) void bucket_sort_kernel(
        const uint_t* __restrict__ pairbuf, const int* __restrict__ indptr,
        int* __restrict__ srcs, int N, int NBK){
    int b = blockIdx.x;
    int nb = b << BK_SHIFT;
    int nend = nb + BK_NODES; if (nend > N) nend = N;
    int beg = indptr[nb], end = indptr[nend];
    int cnt = end - beg;
    __shared__ int lptr[BK_NODES];
    __shared__ int outb[SORT_CAP];
    int t = threadIdx.x;
    if (t < BK_NODES){
        int node = nb + t;
        lptr[t] = (node < N) ? (indptr[node] - beg) : 0;
    }
    __syncthreads();
    if (cnt <= SORT_CAP){
        for (int i = t; i < cnt; i += 256){
            uint_t pr = pairbuf[beg + i];
            int pos = atomicAdd(&lptr[(int)(pr >> 25)], 1);
            outb[pos] = (int)(pr & 0x1FFFFFFu);
        }
        __syncthreads();
        for (int i = t; i < cnt; i += 256) srcs[beg + i] = outb[i];
    } else {
        for (int i = t; i < cnt; i += 256){
            uint_t pr = pairbuf[beg + i];
            int pos = atomicAdd(&lptr[(int)(pr >> 25)], 1);
            srcs[beg + pos] = (int)(pr & 0x1FFFFFFu);
        }
    }
}

// ---------------- layer-1 linear (K=3): xp packed bf16x2 ----------------
__global__ __launch_bounds__(128) void linear_al(
        const float* __restrict__ in, const float* __restrict__ W,
        const float* __restrict__ as_, const float* __restrict__ ad_,
        uint_t* __restrict__ xp16, float* __restrict__ als, float* __restrict__ ald,
        int N, int K){
    __shared__ float hs[8 * 3];
    int t = threadIdx.x;
    int base = blockIdx.x * 8;
    int rows = N - base; if (rows > 8) rows = 8;
    for (int idx = t; idx < rows * K; idx += 128){
        int r = idx / K, k = idx - r * K;
        hs[r * K + k] = in[(size_t)(base + r) * K + k];
    }
    __syncthreads();
    float acc[8] = {0.f,0.f,0.f,0.f,0.f,0.f,0.f,0.f};
    for (int k = 0; k < K; ++k){
        float w = W[k * 128 + t];
        #pragma unroll
        for (int r = 0; r < 8; ++r) acc[r] += hs[r * K + k] * w;
    }
    float asv = as_[t], adv = ad_[t];
    for (int r = 0; r < rows; ++r){
        int row = base + r;
        float v = acc[r];
        float vo = __shfl_xor(v, 1);
        if (!(t & 1)) xp16[(size_t)row * 64 + (t >> 1)] = pack_bf2(v, vo);
        float vs = v * asv, vd = v * adv;
        #pragma unroll
        for (int m = 16; m >= 1; m >>= 1){
            vs += __shfl_xor(vs, m);
            vd += __shfl_xor(vd, m);
        }
        if ((t & 31) == 0){
            int h = t >> 5;
            als[row * 4 + h] = vs;
            ald[row * 4 + h] = vd;
        }
    }
}

// ---------------- W pre-pack into MFMA B-fragment layout (both layers, one launch) ----
// Bpack uint index: cb*1024 + kb*256 + kg*64 + c*4 + u  ->  bf16 pair k=kb*32+kg*8+2u(,+1), col=cb*16+c
__global__ __launch_bounds__(256) void wpack_kernel(
        const float* __restrict__ W2, const float* __restrict__ W3,
        uint_t* __restrict__ B2, uint_t* __restrict__ B3){
    int idx = blockIdx.x * 256 + threadIdx.x;      // 0..16383
    const float* W = (idx < 8192) ? W2 : W3;
    uint_t* Bp = (idx < 8192) ? B2 : B3;
    int i = idx & 8191;
    int u = i & 3, c = (i >> 2) & 15, kg = (i >> 6) & 3, kb = (i >> 8) & 3, cb = (i >> 10) & 7;
    int k = kb * 32 + kg * 8 + 2 * u;
    int col = cb * 16 + c;
    Bp[i] = pack_bf2(W[k * 128 + col], W[(k + 1) * 128 + col]);
}

// ---------------- K=128 linear via MFMA bf16: H(bf16) @ W -> XP(bf16) + als/ald ------
// wave handles a 16-row stripe. A: row=l&15, k=(l>>4)*8+j ; B: col=l&15, same k ;
// D: col=l&15, row=(l>>4)*4+reg  (guide-verified layouts).
__global__ __launch_bounds__(256) void gemm_mfma(
        const uint_t* __restrict__ h16, const uint_t* __restrict__ bpack,
        const float* __restrict__ as_, const float* __restrict__ ad_,
        uint_t* __restrict__ xp16, float* __restrict__ als, float* __restrict__ ald,
        int N){
    int w = threadIdx.x >> 6;
    int l = threadIdx.x & 63;
    int stripe = blockIdx.x * 4 + w;
    int base = stripe * 16;
    if (base >= N) return;
    int r16 = l & 15;
    int kg  = l >> 4;
    int row = base + r16;
    int rowc = row < N ? row : N - 1;

    bf16x8 afr[4];
    const uint4* hrow = (const uint4*)(h16 + (size_t)rowc * 64);
    #pragma unroll
    for (int kb = 0; kb < 4; ++kb) afr[kb] = mk_bf8(hrow[kb * 4 + kg]);

    f32x4 acc[8];
    #pragma unroll
    for (int cb = 0; cb < 8; ++cb) acc[cb] = (f32x4){0.f, 0.f, 0.f, 0.f};

    const uint4* bp = (const uint4*)bpack;
    #pragma unroll
    for (int cb = 0; cb < 8; ++cb){
        #pragma unroll
        for (int kb = 0; kb < 4; ++kb){
            bf16x8 bfr = mk_bf8(bp[((cb * 4 + kb) * 4 + kg) * 16 + r16]);
            acc[cb] = __builtin_amdgcn_mfma_f32_16x16x32_bf16(afr[kb], bfr, acc[cb], 0, 0, 0);
        }
    }

    // epilogue: XP bf16-pack + fused als/ald
    #pragma unroll
    for (int reg = 0; reg < 4; ++reg){
        int ro = base + kg * 4 + reg;
        bool wr = (ro < N) && ((r16 & 1) == 0);
        #pragma unroll
        for (int cb = 0; cb < 8; ++cb){
            float v  = acc[cb][reg];
            float vo = __shfl_xor(v, 1);
            if (wr) xp16[(size_t)ro * 64 + cb * 8 + (r16 >> 1)] = pack_bf2(v, vo);
        }
        #pragma unroll
        for (int h = 0; h < 4; ++h){
            float a0 = as_[h * 32 + r16],      a1 = as_[h * 32 + 16 + r16];
            float g0 = ad_[h * 32 + r16],      g1 = ad_[h * 32 + 16 + r16];
            float ps = acc[2 * h][reg] * a0 + acc[2 * h + 1][reg] * a1;
            float pd = acc[2 * h][reg] * g0 + acc[2 * h + 1][reg] * g1;
            ps += __shfl_xor(ps, 1); ps += __shfl_xor(ps, 2);
            ps += __shfl_xor(ps, 4); ps += __shfl_xor(ps, 8);
            pd += __shfl_xor(pd, 1); pd += __shfl_xor(pd, 2);
            pd += __shfl_xor(pd, 4); pd += __shfl_xor(pd, 8);
            if (r16 == 0 && ro < N){
                als[(size_t)ro * 4 + h] = ps;
                ald[(size_t)ro * 4 + h] = pd;
            }
        }
    }
}

// ---------------- per-node softmax aggregation: one WAVE per node ----------------
// lane l owns channels 2l,2l+1 (head h=l>>4). no max-subtraction; denom reduced once.
// mode 0 writes H packed bf16 (uint per lane).
__global__ __launch_bounds__(256) void gat_agg4(
        const uint_t* __restrict__ xp16, const float4* __restrict__ als,
        const float4* __restrict__ ald,
        const int* __restrict__ indptr, const int* __restrict__ srcs,
        const float* __restrict__ bias,
        uint_t* __restrict__ hout, int N, int mode,
        const float* __restrict__ cW, const float* __restrict__ cb,
        float* __restrict__ fout){
    int wid = threadIdx.x >> 6;
    int l   = threadIdx.x & 63;
    int n = blockIdx.x * 4 + wid;
    __shared__ int   ssh[4][64];
    __shared__ float esh[4][64][4];
    if (n >= N) return;

    int beg = indptr[n], end = indptr[n + 1];
    float4 ad4 = ald[n];
    int h = l >> 4;

    float d0 = 0.f, d1 = 0.f, d2 = 0.f, d3 = 0.f;
    float ax = 0.f, ay = 0.f;

    for (int cbeg = beg; cbeg < end; cbeg += 64){
        int cnt = end - cbeg; if (cnt > 64) cnt = 64;
        if (l < cnt){
            int s = srcs[cbeg + l];
            ssh[wid][l] = s;
            float4 a4 = als[s];
            float p0 = __expf(lrelu(a4.x + ad4.x));
            float p1 = __expf(lrelu(a4.y + ad4.y));
            float p2 = __expf(lrelu(a4.z + ad4.z));
            float p3 = __expf(lrelu(a4.w + ad4.w));
            *((float4*)&esh[wid][l][0]) = make_float4(p0, p1, p2, p3);
            d0 += p0; d1 += p1; d2 += p2; d3 += p3;
        }
        __builtin_amdgcn_wave_barrier();

        int j = 0;
        for (; j + 8 <= cnt; j += 8){
            int s0 = ssh[wid][j+0]; float w0 = esh[wid][j+0][h];
            int s1 = ssh[wid][j+1]; float w1 = esh[wid][j+1][h];
            int s2 = ssh[wid][j+2]; float w2 = esh[wid][j+2][h];
            int s3 = ssh[wid][j+3]; float w3 = esh[wid][j+3][h];
            int s4 = ssh[wid][j+4]; float w4 = esh[wid][j+4][h];
            int s5 = ssh[wid][j+5]; float w5 = esh[wid][j+5][h];
            int s6 = ssh[wid][j+6]; float w6 = esh[wid][j+6][h];
            int s7 = ssh[wid][j+7]; float w7 = esh[wid][j+7][h];
            uint_t u0 = xp16[(size_t)s0 * 64 + l];
            uint_t u1 = xp16[(size_t)s1 * 64 + l];
            uint_t u2 = xp16[(size_t)s2 * 64 + l];
            uint_t u3 = xp16[(size_t)s3 * 64 + l];
            uint_t u4 = xp16[(size_t)s4 * 64 + l];
            uint_t u5 = xp16[(size_t)s5 * 64 + l];
            uint_t u6 = xp16[(size_t)s6 * 64 + l];
            uint_t u7 = xp16[(size_t)s7 * 64 + l];
            ax = fmaf(bflo(u0), w0, ax); ay = fmaf(bfhi(u0), w0, ay);
            ax = fmaf(bflo(u1), w1, ax); ay = fmaf(bfhi(u1), w1, ay);
            ax = fmaf(bflo(u2), w2, ax); ay = fmaf(bfhi(u2), w2, ay);
            ax = fmaf(bflo(u3), w3, ax); ay = fmaf(bfhi(u3), w3, ay);
            ax = fmaf(bflo(u4), w4, ax); ay = fmaf(bfhi(u4), w4, ay);
            ax = fmaf(bflo(u5), w5, ax); ay = fmaf(bfhi(u5), w5, ay);
            ax = fmaf(bflo(u6), w6, ax); ay = fmaf(bfhi(u6), w6, ay);
            ax = fmaf(bflo(u7), w7, ax); ay = fmaf(bfhi(u7), w7, ay);
        }
        for (; j < cnt; ++j){
            int s = ssh[wid][j];
            float w = esh[wid][j][h];
            uint_t u = xp16[(size_t)s * 64 + l];
            ax = fmaf(bflo(u), w, ax);
            ay = fmaf(bfhi(u), w, ay);
        }
    }

    d0 = wsum(d0); d1 = wsum(d1); d2 = wsum(d2); d3 = wsum(d3);

    float dh = sel4(d0, d1, d2, d3, h);
    float inv = 1.f / (dh + 1e-16f);
    float2 b2 = ((const float2*)bias)[l];
    float vx = ax * inv + b2.x;
    float vy = ay * inv + b2.y;
    vx = vx > 0.f ? vx : (__expf(vx) - 1.f);
    vy = vy > 0.f ? vy : (__expf(vy) - 1.f);

    if (mode == 0){
        hout[(size_t)n * 64 + l] = pack_bf2(vx, vy);
    } else {
        float2 cw2 = ((const float2*)cW)[l];
        float p = vx * cw2.x + vy * cw2.y;
        p = wsum(p);
        if (l == 0){
            float logit = p + cb[0];
            fout[n] = 1.f / (1.f + __expf(-logit));
        }
    }
}

extern "C" void kernel_launch(void* const* d_in, const int* in_sizes, int n_in,
                              void* d_out, int out_size, void* d_ws, size_t ws_size,
                              hipStream_t stream){
    const float* x   = (const float*)d_in[0];
    const int*   ei  = (const int*)d_in[1];
    const float* W1  = (const float*)d_in[2];
    const float* as1 = (const float*)d_in[3];
    const float* ad1 = (const float*)d_in[4];
    const float* b1  = (const float*)d_in[5];
    const float* W2  = (const float*)d_in[6];
    const float* as2 = (const float*)d_in[7];
    const float* ad2 = (const float*)d_in[8];
    const float* b2  = (const float*)d_in[9];
    const float* W3  = (const float*)d_in[10];
    const float* as3 = (const float*)d_in[11];
    const float* ad3 = (const float*)d_in[12];
    const float* b3  = (const float*)d_in[13];
    const float* cW  = (const float*)d_in[14];
    const float* cb  = (const float*)d_in[15];
    float* out = (float*)d_out;

    int N = in_sizes[0] / 3;
    int E = in_sizes[1] / 2;
    int EN = E + N;
    int NBK = (N + BK_NODES - 1) / BK_NODES;

    char* ws = (char*)d_ws;
    size_t off = 0;
    auto alloc = [&](size_t bytes) -> void* {
        void* p = ws + off;
        off += (bytes + 255) & ~(size_t)255;
        return p;
    };
    int*    deg     = (int*)alloc((size_t)N * 4);
    int*    indptr  = (int*)alloc((size_t)(N + 1) * 4);
    int*    srcs    = (int*)alloc((size_t)EN * 4);
    uint_t* pairbuf = (uint_t*)alloc((size_t)EN * 4);
    uint_t* XP      = (uint_t*)alloc((size_t)N * 64 * 4);   // packed bf16x2
    uint_t* H16     = (uint_t*)alloc((size_t)N * 64 * 4);   // packed bf16x2
    float*  ALS     = (float*)alloc((size_t)N * 4 * 4);
    float*  ALD     = (float*)alloc((size_t)N * 4 * 4);
    int*    bsum    = (int*)alloc((size_t)1024 * 4);
    int*    gcursor = (int*)alloc((size_t)MAXBK * 4);
    uint_t* BP2     = (uint_t*)alloc((size_t)8192 * 4);
    uint_t* BP3     = (uint_t*)alloc((size_t)8192 * 4);
    (void)ws_size;

    int NB = (N + 1023) / 1024;

    hipMemsetAsync(deg, 0, (size_t)N * 4, stream);
    hist_kernel<<<(EN + 255) / 256, 256, 0, stream>>>(ei, E, N, deg);
    scan_blocksum<<<NB, 256, 0, stream>>>(deg, bsum, N);
    scan_partials<<<1, 1024, 0, stream>>>(bsum, NB, indptr, N);
    scan_final<<<NB, 256, 0, stream>>>(deg, bsum, indptr, gcursor, N);
    partition_kernel<<<(EN + PART_CHUNK - 1) / PART_CHUNK, 256, 0, stream>>>(
        ei, E, N, gcursor, pairbuf, NBK);
    bucket_sort_kernel<<<NBK, 256, 0, stream>>>(pairbuf, indptr, srcs, N, NBK);
    wpack_kernel<<<64, 256, 0, stream>>>(W2, W3, BP2, BP3);

    int ab = (N + 3) / 4;
    int gb = ((N + 15) / 16 + 3) / 4;
    // layer 1 (K=3)
    linear_al<<<(N + 7) / 8, 128, 0, stream>>>(x, W1, as1, ad1, XP, ALS, ALD, N, 3);
    gat_agg4<<<ab, 256, 0, stream>>>(XP, (const float4*)ALS, (const float4*)ALD,
                                     indptr, srcs, b1, H16, N, 0, nullptr, nullptr, nullptr);
    // layer 2 (MFMA)
    gemm_mfma<<<gb, 256, 0, stream>>>(H16, BP2, as2, ad2, XP, ALS, ALD, N);
    gat_agg4<<<ab, 256, 0, stream>>>(XP, (const float4*)ALS, (const float4*)ALD,
                                     indptr, srcs, b2, H16, N, 0, nullptr, nullptr, nullptr);
    // layer 3 (MFMA) + fused classifier
    gemm_mfma<<<gb, 256, 0, stream>>>(H16, BP3, as3, ad3, XP, ALS, ALD, N);
    gat_agg4<<<ab, 256, 0, stream>>>(XP, (const float4*)ALS, (const float4*)ALD,
                                     indptr, srcs, b3, nullptr, N, 1, cW, cb, out);
}

// Round 9
// 227.261 us; speedup vs baseline: 1.6225x; 1.1543x over previous
//
#include <hip/hip_runtime.h>
#include <math.h>

typedef unsigned int uint_t;
typedef __attribute__((ext_vector_type(8))) short bf16x8;
typedef __attribute__((ext_vector_type(4))) float f32x4;

#define BK_SHIFT 7
#define BK_NODES 128
#define MAXBK 512          // supports N <= 65536
#define PART_CHUNK 4096
#define SORT_CAP 4096

__device__ __forceinline__ float lrelu(float x){ return x > 0.f ? x : 0.2f*x; }
__device__ __forceinline__ float sel4(float a, float b, float c, float d, int h){
    return h==0 ? a : (h==1 ? b : (h==2 ? c : d));
}
__device__ __forceinline__ float wsum(float v){
    #pragma unroll
    for (int m = 1; m < 64; m <<= 1) v += __shfl_xor(v, m);
    return v;
}
__device__ __forceinline__ uint_t pack_bf2(float a, float b){
    uint_t ua = __float_as_uint(a); uint_t ub = __float_as_uint(b);
    ua += 0x7FFFu + ((ua >> 16) & 1u);
    ub += 0x7FFFu + ((ub >> 16) & 1u);
    return (ua >> 16) | (ub & 0xFFFF0000u);
}
__device__ __forceinline__ float bflo(uint_t u){ return __uint_as_float(u << 16); }
__device__ __forceinline__ float bfhi(uint_t u){ return __uint_as_float(u & 0xFFFF0000u); }
__device__ __forceinline__ bf16x8 mk_bf8(uint4 u){
    bf16x8 r;
    r[0]=(short)(u.x & 0xFFFFu); r[1]=(short)(u.x >> 16);
    r[2]=(short)(u.y & 0xFFFFu); r[3]=(short)(u.y >> 16);
    r[4]=(short)(u.z & 0xFFFFu); r[5]=(short)(u.z >> 16);
    r[6]=(short)(u.w & 0xFFFFu); r[7]=(short)(u.w >> 16);
    return r;
}

// ---------------- CSR build (bucket-level) ----------------

// a) bucket histogram, coalesced reads, LDS-staged
__global__ __launch_bounds__(256) void bucket_count(const int* __restrict__ ei, int E, int N,
                                                    int* __restrict__ bkcnt){
    __shared__ int h[MAXBK];
    int t = threadIdx.x;
    for (int i = t; i < MAXBK; i += 256) h[i] = 0;
    __syncthreads();
    int base = blockIdx.x * PART_CHUNK;
    int cnt = E + N - base; if (cnt > PART_CHUNK) cnt = PART_CHUNK; if (cnt < 0) cnt = 0;
    for (int i = t; i < cnt; i += 256){
        int idx = base + i;
        int d = (idx < E) ? ei[E + idx] : (idx - E);
        atomicAdd(&h[d >> BK_SHIFT], 1);
    }
    __syncthreads();
    for (int i = t; i < MAXBK; i += 256) if (h[i]) atomicAdd(&bkcnt[i], h[i]);
}

// b) exclusive scan of 512 bucket counts -> bkoff[0..NBK] (+gcursor copy)
__global__ __launch_bounds__(512) void bucket_scan(const int* __restrict__ bkcnt,
                                                   int* __restrict__ bkoff,
                                                   int* __restrict__ gcursor,
                                                   int NBK, int EN){
    int t = threadIdx.x;
    __shared__ int sm[MAXBK];
    sm[t] = (t < NBK) ? bkcnt[t] : 0;
    __syncthreads();
    for (int off = 1; off < MAXBK; off <<= 1){
        int u = (t >= off) ? sm[t - off] : 0;
        __syncthreads();
        sm[t] += u;
        __syncthreads();
    }
    int excl = (t == 0) ? 0 : sm[t - 1];
    if (t < NBK){ bkoff[t] = excl; gcursor[t] = excl; }
    if (t == 0) bkoff[NBK] = EN;
}

// c) partition packed (src | dlow<<25) into bucket-contiguous pairbuf
__global__ __launch_bounds__(256) void partition_kernel(
        const int* __restrict__ ei, int E, int N,
        int* __restrict__ gcursor, uint_t* __restrict__ pairbuf, int NBK){
    __shared__ int hist[MAXBK];
    __shared__ int sA[MAXBK];
    __shared__ int destadj[MAXBK];
    __shared__ int cnt2[MAXBK];
    __shared__ uint_t staged[PART_CHUNK];
    __shared__ unsigned short sbk[PART_CHUNK];
    int t = threadIdx.x;
    int base = blockIdx.x * PART_CHUNK;
    int total = E + N;
    int cnt = total - base; if (cnt > PART_CHUNK) cnt = PART_CHUNK; if (cnt < 0) cnt = 0;

    for (int i = t; i < MAXBK; i += 256){ hist[i] = 0; cnt2[i] = 0; }
    __syncthreads();
    for (int i = t; i < cnt; i += 256){
        int idx = base + i;
        int d = (idx < E) ? ei[E + idx] : (idx - E);
        atomicAdd(&hist[d >> BK_SHIFT], 1);
    }
    __syncthreads();
    sA[t] = hist[t]; sA[t + 256] = hist[t + 256];
    __syncthreads();
    for (int off = 1; off < MAXBK; off <<= 1){
        int i0 = t, i1 = t + 256;
        int a0 = sA[i0] + ((i0 >= off) ? sA[i0 - off] : 0);
        int a1 = sA[i1] + ((i1 >= off) ? sA[i1 - off] : 0);
        __syncthreads();
        sA[i0] = a0; sA[i1] = a1;
        __syncthreads();
    }
    for (int b = t; b < NBK; b += 256){
        int c = hist[b];
        int gstart = (b == 0) ? 0 : sA[b - 1];
        int rbase = c > 0 ? atomicAdd(&gcursor[b], c) : 0;
        destadj[b] = rbase - gstart;
        cnt2[b] = gstart;
    }
    __syncthreads();
    for (int i = t; i < cnt; i += 256){
        int idx = base + i;
        int d, s;
        if (idx < E){ s = ei[idx]; d = ei[E + idx]; }
        else        { s = d = idx - E; }
        int b = d >> BK_SHIFT;
        int pos = atomicAdd(&cnt2[b], 1);
        staged[pos] = (uint_t)s | ((uint_t)(d & (BK_NODES - 1)) << 25);
        sbk[pos] = (unsigned short)b;
    }
    __syncthreads();
    for (int p = t; p < cnt; p += 256){
        int b = (int)sbk[p];
        pairbuf[destadj[b] + p] = staged[p];
    }
}

// d) per-bucket counting sort; ALSO derives per-node indptr (LDS 128-hist + scan)
__global__ __launch_bounds__(256) void bucket_sort2(
        const uint_t* __restrict__ pairbuf, const int* __restrict__ bkoff,
        int* __restrict__ indptr, int* __restrict__ srcs, int N, int NBK, int EN){
    int b = blockIdx.x;
    int beg = bkoff[b], end = bkoff[b + 1];
    int cnt = end - beg;
    int nb = b << BK_SHIFT;
    __shared__ int nh[BK_NODES];
    __shared__ int noff[BK_NODES];
    __shared__ int outb[SORT_CAP];
    int t = threadIdx.x;
    if (t < BK_NODES) nh[t] = 0;
    __syncthreads();
    for (int i = t; i < cnt; i += 256){
        uint_t pr = pairbuf[beg + i];
        atomicAdd(&nh[(int)(pr >> 25)], 1);
    }
    __syncthreads();
    if (t < BK_NODES) noff[t] = nh[t];
    __syncthreads();
    for (int off = 1; off < BK_NODES; off <<= 1){
        int u = 0;
        if (t < BK_NODES && t >= off) u = noff[t - off];
        __syncthreads();
        if (t < BK_NODES) noff[t] += u;
        __syncthreads();
    }
    if (t < BK_NODES){
        int excl = noff[t] - nh[t];
        int node = nb + t;
        if (node < N) indptr[node] = beg + excl;
        nh[t] = excl;                 // reuse as local cursor
    }
    if (b == NBK - 1 && t == 0) indptr[N] = EN;
    __syncthreads();
    if (cnt <= SORT_CAP){
        for (int i = t; i < cnt; i += 256){
            uint_t pr = pairbuf[beg + i];
            int pos = atomicAdd(&nh[(int)(pr >> 25)], 1);
            outb[pos] = (int)(pr & 0x1FFFFFFu);
        }
        __syncthreads();
        for (int i = t; i < cnt; i += 256) srcs[beg + i] = outb[i];
    } else {
        for (int i = t; i < cnt; i += 256){
            uint_t pr = pairbuf[beg + i];
            int pos = atomicAdd(&nh[(int)(pr >> 25)], 1);
            srcs[beg + pos] = (int)(pr & 0x1FFFFFFu);
        }
    }
}

// ---------------- layer-1 linear (K=3): xp packed bf16x2 ----------------
__global__ __launch_bounds__(128) void linear_al(
        const float* __restrict__ in, const float* __restrict__ W,
        const float* __restrict__ as_, const float* __restrict__ ad_,
        uint_t* __restrict__ xp16, float* __restrict__ als, float* __restrict__ ald,
        int N, int K){
    __shared__ float hs[8 * 3];
    int t = threadIdx.x;
    int base = blockIdx.x * 8;
    int rows = N - base; if (rows > 8) rows = 8;
    for (int idx = t; idx < rows * K; idx += 128){
        int r = idx / K, k = idx - r * K;
        hs[r * K + k] = in[(size_t)(base + r) * K + k];
    }
    __syncthreads();
    float acc[8] = {0.f,0.f,0.f,0.f,0.f,0.f,0.f,0.f};
    for (int k = 0; k < K; ++k){
        float w = W[k * 128 + t];
        #pragma unroll
        for (int r = 0; r < 8; ++r) acc[r] += hs[r * K + k] * w;
    }
    float asv = as_[t], adv = ad_[t];
    for (int r = 0; r < rows; ++r){
        int row = base + r;
        float v = acc[r];
        float vo = __shfl_xor(v, 1);
        if (!(t & 1)) xp16[(size_t)row * 64 + (t >> 1)] = pack_bf2(v, vo);
        float vs = v * asv, vd = v * adv;
        #pragma unroll
        for (int m = 16; m >= 1; m >>= 1){
            vs += __shfl_xor(vs, m);
            vd += __shfl_xor(vd, m);
        }
        if ((t & 31) == 0){
            int h = t >> 5;
            als[row * 4 + h] = vs;
            ald[row * 4 + h] = vd;
        }
    }
}

// ---------------- W pre-pack into MFMA B-fragment layout ----------------
__global__ __launch_bounds__(256) void wpack_kernel(
        const float* __restrict__ W2, const float* __restrict__ W3,
        uint_t* __restrict__ B2, uint_t* __restrict__ B3){
    int idx = blockIdx.x * 256 + threadIdx.x;      // 0..16383
    const float* W = (idx < 8192) ? W2 : W3;
    uint_t* Bp = (idx < 8192) ? B2 : B3;
    int i = idx & 8191;
    int u = i & 3, c = (i >> 2) & 15, kg = (i >> 6) & 3, kb = (i >> 8) & 3, cb = (i >> 10) & 7;
    int k = kb * 32 + kg * 8 + 2 * u;
    int col = cb * 16 + c;
    Bp[i] = pack_bf2(W[k * 128 + col], W[(k + 1) * 128 + col]);
}

// ---------------- K=128 linear via MFMA bf16 ----------------
__global__ __launch_bounds__(256) void gemm_mfma(
        const uint_t* __restrict__ h16, const uint_t* __restrict__ bpack,
        const float* __restrict__ as_, const float* __restrict__ ad_,
        uint_t* __restrict__ xp16, float* __restrict__ als, float* __restrict__ ald,
        int N){
    int w = threadIdx.x >> 6;
    int l = threadIdx.x & 63;
    int stripe = blockIdx.x * 4 + w;
    int base = stripe * 16;
    if (base >= N) return;
    int r16 = l & 15;
    int kg  = l >> 4;
    int row = base + r16;
    int rowc = row < N ? row : N - 1;

    bf16x8 afr[4];
    const uint4* hrow = (const uint4*)(h16 + (size_t)rowc * 64);
    #pragma unroll
    for (int kb = 0; kb < 4; ++kb) afr[kb] = mk_bf8(hrow[kb * 4 + kg]);

    f32x4 acc[8];
    #pragma unroll
    for (int cb = 0; cb < 8; ++cb) acc[cb] = (f32x4){0.f, 0.f, 0.f, 0.f};

    const uint4* bp = (const uint4*)bpack;
    #pragma unroll
    for (int cb = 0; cb < 8; ++cb){
        #pragma unroll
        for (int kb = 0; kb < 4; ++kb){
            bf16x8 bfr = mk_bf8(bp[((cb * 4 + kb) * 4 + kg) * 16 + r16]);
            acc[cb] = __builtin_amdgcn_mfma_f32_16x16x32_bf16(afr[kb], bfr, acc[cb], 0, 0, 0);
        }
    }

    #pragma unroll
    for (int reg = 0; reg < 4; ++reg){
        int ro = base + kg * 4 + reg;
        bool wr = (ro < N) && ((r16 & 1) == 0);
        #pragma unroll
        for (int cb = 0; cb < 8; ++cb){
            float v  = acc[cb][reg];
            float vo = __shfl_xor(v, 1);
            if (wr) xp16[(size_t)ro * 64 + cb * 8 + (r16 >> 1)] = pack_bf2(v, vo);
        }
        #pragma unroll
        for (int h = 0; h < 4; ++h){
            float a0 = as_[h * 32 + r16],      a1 = as_[h * 32 + 16 + r16];
            float g0 = ad_[h * 32 + r16],      g1 = ad_[h * 32 + 16 + r16];
            float ps = acc[2 * h][reg] * a0 + acc[2 * h + 1][reg] * a1;
            float pd = acc[2 * h][reg] * g0 + acc[2 * h + 1][reg] * g1;
            ps += __shfl_xor(ps, 1); ps += __shfl_xor(ps, 2);
            ps += __shfl_xor(ps, 4); ps += __shfl_xor(ps, 8);
            pd += __shfl_xor(pd, 1); pd += __shfl_xor(pd, 2);
            pd += __shfl_xor(pd, 4); pd += __shfl_xor(pd, 8);
            if (r16 == 0 && ro < N){
                als[(size_t)ro * 4 + h] = ps;
                ald[(size_t)ro * 4 + h] = pd;
            }
        }
    }
}

// ---------------- per-node softmax aggregation: one WAVE per node ----------------
// lane l owns channels 2l,2l+1 (head h=l>>4). 16-deep gather batches for MLP;
// __launch_bounds__(256,8) pins 8 waves/EU occupancy.
__global__ __launch_bounds__(256, 8) void gat_agg4(
        const uint_t* __restrict__ xp16, const float4* __restrict__ als,
        const float4* __restrict__ ald,
        const int* __restrict__ indptr, const int* __restrict__ srcs,
        const float* __restrict__ bias,
        uint_t* __restrict__ hout, int N, int mode,
        const float* __restrict__ cW, const float* __restrict__ cb,
        float* __restrict__ fout){
    int wid = threadIdx.x >> 6;
    int l   = threadIdx.x & 63;
    int n = blockIdx.x * 4 + wid;
    __shared__ int   ssh[4][64];
    __shared__ float esh[4][64][4];
    if (n >= N) return;

    int beg = indptr[n], end = indptr[n + 1];
    float4 ad4 = ald[n];
    int h = l >> 4;

    float d0 = 0.f, d1 = 0.f, d2 = 0.f, d3 = 0.f;
    float ax = 0.f, ay = 0.f;

    for (int cbeg = beg; cbeg < end; cbeg += 64){
        int cnt = end - cbeg; if (cnt > 64) cnt = 64;
        if (l < cnt){
            int s = srcs[cbeg + l];
            ssh[wid][l] = s;
            float4 a4 = als[s];
            float p0 = __expf(lrelu(a4.x + ad4.x));
            float p1 = __expf(lrelu(a4.y + ad4.y));
            float p2 = __expf(lrelu(a4.z + ad4.z));
            float p3 = __expf(lrelu(a4.w + ad4.w));
            *((float4*)&esh[wid][l][0]) = make_float4(p0, p1, p2, p3);
            d0 += p0; d1 += p1; d2 += p2; d3 += p3;
        }
        __builtin_amdgcn_wave_barrier();

        int j = 0;
        for (; j + 16 <= cnt; j += 16){
            int ss[16]; float ww[16]; uint_t uu[16];
            #pragma unroll
            for (int q = 0; q < 16; ++q){ ss[q] = ssh[wid][j+q]; ww[q] = esh[wid][j+q][h]; }
            #pragma unroll
            for (int q = 0; q < 16; ++q) uu[q] = xp16[(size_t)ss[q] * 64 + l];
            #pragma unroll
            for (int q = 0; q < 16; ++q){
                ax = fmaf(bflo(uu[q]), ww[q], ax);
                ay = fmaf(bfhi(uu[q]), ww[q], ay);
            }
        }
        for (; j + 8 <= cnt; j += 8){
            int ss[8]; float ww[8]; uint_t uu[8];
            #pragma unroll
            for (int q = 0; q < 8; ++q){ ss[q] = ssh[wid][j+q]; ww[q] = esh[wid][j+q][h]; }
            #pragma unroll
            for (int q = 0; q < 8; ++q) uu[q] = xp16[(size_t)ss[q] * 64 + l];
            #pragma unroll
            for (int q = 0; q < 8; ++q){
                ax = fmaf(bflo(uu[q]), ww[q], ax);
                ay = fmaf(bfhi(uu[q]), ww[q], ay);
            }
        }
        for (; j < cnt; ++j){
            int s = ssh[wid][j];
            float w = esh[wid][j][h];
            uint_t u = xp16[(size_t)s * 64 + l];
            ax = fmaf(bflo(u), w, ax);
            ay = fmaf(bfhi(u), w, ay);
        }
    }

    d0 = wsum(d0); d1 = wsum(d1); d2 = wsum(d2); d3 = wsum(d3);

    float dh = sel4(d0, d1, d2, d3, h);
    float inv = 1.f / (dh + 1e-16f);
    float2 b2 = ((const float2*)bias)[l];
    float vx = ax * inv + b2.x;
    float vy = ay * inv + b2.y;
    vx = vx > 0.f ? vx : (__expf(vx) - 1.f);
    vy = vy > 0.f ? vy : (__expf(vy) - 1.f);

    if (mode == 0){
        hout[(size_t)n * 64 + l] = pack_bf2(vx, vy);
    } else {
        float2 cw2 = ((const float2*)cW)[l];
        float p = vx * cw2.x + vy * cw2.y;
        p = wsum(p);
        if (l == 0){
            float logit = p + cb[0];
            fout[n] = 1.f / (1.f + __expf(-logit));
        }
    }
}

extern "C" void kernel_launch(void* const* d_in, const int* in_sizes, int n_in,
                              void* d_out, int out_size, void* d_ws, size_t ws_size,
                              hipStream_t stream){
    const float* x   = (const float*)d_in[0];
    const int*   ei  = (const int*)d_in[1];
    const float* W1  = (const float*)d_in[2];
    const float* as1 = (const float*)d_in[3];
    const float* ad1 = (const float*)d_in[4];
    const float* b1  = (const float*)d_in[5];
    const float* W2  = (const float*)d_in[6];
    const float* as2 = (const float*)d_in[7];
    const float* ad2 = (const float*)d_in[8];
    const float* b2  = (const float*)d_in[9];
    const float* W3  = (const float*)d_in[10];
    const float* as3 = (const float*)d_in[11];
    const float* ad3 = (const float*)d_in[12];
    const float* b3  = (const float*)d_in[13];
    const float* cW  = (const float*)d_in[14];
    const float* cb  = (const float*)d_in[15];
    float* out = (float*)d_out;

    int N = in_sizes[0] / 3;
    int E = in_sizes[1] / 2;
    int EN = E + N;
    int NBK = (N + BK_NODES - 1) / BK_NODES;

    char* ws = (char*)d_ws;
    size_t off = 0;
    auto alloc = [&](size_t bytes) -> void* {
        void* p = ws + off;
        off += (bytes + 255) & ~(size_t)255;
        return p;
    };
    int*    indptr  = (int*)alloc((size_t)(N + 1) * 4);
    int*    srcs    = (int*)alloc((size_t)EN * 4);
    uint_t* pairbuf = (uint_t*)alloc((size_t)EN * 4);
    uint_t* XP      = (uint_t*)alloc((size_t)N * 64 * 4);   // packed bf16x2
    uint_t* H16     = (uint_t*)alloc((size_t)N * 64 * 4);   // packed bf16x2
    float*  ALS     = (float*)alloc((size_t)N * 4 * 4);
    float*  ALD     = (float*)alloc((size_t)N * 4 * 4);
    int*    bkcnt   = (int*)alloc((size_t)MAXBK * 4);
    int*    bkoff   = (int*)alloc((size_t)(MAXBK + 1) * 4);
    int*    gcursor = (int*)alloc((size_t)MAXBK * 4);
    uint_t* BP2     = (uint_t*)alloc((size_t)8192 * 4);
    uint_t* BP3     = (uint_t*)alloc((size_t)8192 * 4);
    (void)ws_size;

    int pb = (EN + PART_CHUNK - 1) / PART_CHUNK;

    hipMemsetAsync(bkcnt, 0, (size_t)MAXBK * 4, stream);
    bucket_count<<<pb, 256, 0, stream>>>(ei, E, N, bkcnt);
    bucket_scan<<<1, 512, 0, stream>>>(bkcnt, bkoff, gcursor, NBK, EN);
    partition_kernel<<<pb, 256, 0, stream>>>(ei, E, N, gcursor, pairbuf, NBK);
    bucket_sort2<<<NBK, 256, 0, stream>>>(pairbuf, bkoff, indptr, srcs, N, NBK, EN);
    wpack_kernel<<<64, 256, 0, stream>>>(W2, W3, BP2, BP3);

    int ab = (N + 3) / 4;
    int gb = ((N + 15) / 16 + 3) / 4;
    // layer 1 (K=3)
    linear_al<<<(N + 7) / 8, 128, 0, stream>>>(x, W1, as1, ad1, XP, ALS, ALD, N, 3);
    gat_agg4<<<ab, 256, 0, stream>>>(XP, (const float4*)ALS, (const float4*)ALD,
                                     indptr, srcs, b1, H16, N, 0, nullptr, nullptr, nullptr);
    // layer 2 (MFMA)
    gemm_mfma<<<gb, 256, 0, stream>>>(H16, BP2, as2, ad2, XP, ALS, ALD, N);
    gat_agg4<<<ab, 256, 0, stream>>>(XP, (const float4*)ALS, (const float4*)ALD,
                                     indptr, srcs, b2, H16, N, 0, nullptr, nullptr, nullptr);
    // layer 3 (MFMA) + fused classifier
    gemm_mfma<<<gb, 256, 0, stream>>>(H16, BP3, as3, ad3, XP, ALS, ALD, N);
    gat_agg4<<<ab, 256, 0, stream>>>(XP, (const float4*)ALS, (const float4*)ALD,
                                     indptr, srcs, b3, nullptr, N, 1, cW, cb, out);
}